// Round 5
// baseline (58.480 us; speedup 1.0000x reference)
//
#include <hip/hip_runtime.h>
#include <hip/hip_bf16.h>
#include <math.h>

#define CCH   256      // IN_CHANNELS
#define HH    128
#define WW    128
#define EPSF  1e-12f
#define EPS81 8.1e-11f // 81 * 1e-12
#define SLOPE 0.2f

// pooled layout: [3][N][512]  (c -> mean part, 256+c -> std part)

__device__ __forceinline__ void k3_loadrow(const float* __restrict__ plane, int r, int jb,
                                           float4& rs, float4& rq) {
    const float* rp = &plane[r * WW + jb];
    float4 v = *reinterpret_cast<const float4*>(rp);       // cols jb..jb+3 (16B aligned)
    float2 w = *reinterpret_cast<const float2*>(rp + 4);   // cols jb+4, jb+5 (8B aligned)
    float t12 = v.y + v.z, t34 = v.w + w.x;
    rs.x = v.x + t12; rs.y = t12 + v.w; rs.z = v.z + t34; rs.w = t34 + w.y;
    float y0 = v.x * v.x, y1 = v.y * v.y, y2 = v.z * v.z;
    float y3 = v.w * v.w, y4 = w.x * w.x, y5 = w.y * w.y;
    float u12 = y1 + y2, u34 = y3 + y4;
    rq.x = y0 + u12; rq.y = u12 + y3; rq.z = y2 + u34; rq.w = u34 + y5;
}

__device__ __forceinline__ void win_acc(float S, float Q, float wm, float& aS, float& aD) {
    // std*9 = sqrt(max(9Q - S^2, 0) + 81*eps); accumulate masked
    float d = fmaxf(fmaf(S, -S, 9.f * Q), 0.f);
    aS = fmaf(wm, S, aS);
    aD = fmaf(wm, sqrtf(d + EPS81), aD);
}

__global__ __launch_bounds__(512, 4) void stats_kernel(const float* __restrict__ feat,
                                                       float* __restrict__ pooled,
                                                       int N) {
    __shared__ float plane[HH * WW + 8];      // 64 KB + pad
    __shared__ float wp[8][6];

    const int p    = blockIdx.x;              // n*C + c
    const int n    = p >> 8;
    const int c    = p & 255;
    const int tid  = threadIdx.x;
    const int wave = tid >> 6, lane = tid & 63;

    // ---- stage plane into LDS via async global->LDS (16B/lane, linear layout) ----
    {
        const float* gbase = feat + (size_t)p * (HH * WW) + (tid << 2);
        #pragma unroll
        for (int i = 0; i < 8; ++i) {
            __builtin_amdgcn_global_load_lds(
                (const __attribute__((address_space(1))) void*)(gbase + i * 2048),
                (__attribute__((address_space(3))) void*)&plane[i * 2048 + (wave << 8)],
                16, 0, 0);
        }
        if (tid < 8) plane[HH * WW + tid] = 0.f;
    }
    __syncthreads();

    // =============== K = 3, stride 1, out 126x126 ===============
    // thread = (strip s: window cols 4s..4s+3, rowgroup g: window rows 8g..8g+7)
    // Branchless: all 8 row-steps run; invalid windows masked; row index clamped.
    float a3S = 0.f, a3D = 0.f;
    {
        const int s  = tid & 31;
        const int g  = tid >> 5;              // 0..15
        const int jb = s << 2;
        const float wm2 = (s < 31) ? 1.f : 0.f;  // window cols 4s+2,4s+3 invalid for s=31
        const int i0 = g << 3;
        float4 r0s, r0q, r1s, r1q;
        k3_loadrow(plane, i0,     jb, r0s, r0q);
        k3_loadrow(plane, i0 + 1, jb, r1s, r1q);
        #pragma unroll
        for (int t = 0; t < 8; ++t) {
            const int i  = i0 + t;
            const int r2 = (i + 2 < 128) ? (i + 2) : 127;   // clamp (g=15 tail)
            float4 r2s, r2q;
            k3_loadrow(plane, r2, jb, r2s, r2q);
            const float wr  = (i < 126) ? 1.f : 0.f;        // row validity mask
            const float wrm = wr * wm2;
            float Sx = r0s.x + r1s.x + r2s.x, Qx = r0q.x + r1q.x + r2q.x;
            float Sy = r0s.y + r1s.y + r2s.y, Qy = r0q.y + r1q.y + r2q.y;
            float Sz = r0s.z + r1s.z + r2s.z, Qz = r0q.z + r1q.z + r2q.z;
            float Sw = r0s.w + r1s.w + r2s.w, Qw = r0q.w + r1q.w + r2q.w;
            win_acc(Sx, Qx, wr,  a3S, a3D);
            win_acc(Sy, Qy, wr,  a3S, a3D);
            win_acc(Sz, Qz, wrm, a3S, a3D);
            win_acc(Sw, Qw, wrm, a3S, a3D);
            r0s = r1s; r0q = r1q; r1s = r2s; r1q = r2q;
        }
    }

    // =============== K = 34, stride 16, out 6x6 (windows round-robin over 8 waves) ===============
    float am34 = 0.f, as34 = 0.f;
    for (int w = wave; w < 36; w += 8) {
        int wi = w / 6, wj = w - 6 * wi;
        int r0 = wi << 4, c0 = wj << 4;
        float S = 0.f, Q = 0.f;
        #pragma unroll
        for (int it = 0; it < 5; ++it) {
            int t = lane + (it << 6);
            if (t < 306) {                     // 34 rows x 9 float4-slots
                int r = t / 9, c4 = t - 9 * r;
                const float* rp = &plane[(r0 + r) * WW + c0 + (c4 << 2)];
                float4 v = *reinterpret_cast<const float4*>(rp);
                if (c4 == 8) { v.z = 0.f; v.w = 0.f; }   // cols 34,35 of window masked
                S += (v.x + v.y) + (v.z + v.w);
                Q = fmaf(v.x, v.x, Q); Q = fmaf(v.y, v.y, Q);
                Q = fmaf(v.z, v.z, Q); Q = fmaf(v.w, v.w, Q);
            }
        }
        #pragma unroll
        for (int off = 32; off > 0; off >>= 1) {
            S += __shfl_down(S, off);
            Q += __shfl_down(Q, off);
        }
        if (lane == 0) {
            const float inv = 1.f / 1156.f;
            float mean = S * inv;
            float var  = fmaxf(fmaf(-mean, mean, Q * inv), 0.f);
            am34 += mean;
            as34 += sqrtf(var + EPSF);
        }
    }

    // =============== K = 65, stride 32, out 2x2 (one window per wave, waves 4..7) ===============
    float m65 = 0.f, s65 = 0.f;
    if (wave >= 4) {
        int w  = wave - 4;
        int wi = w >> 1, wj = w & 1;
        int r0 = wi << 5, c0 = wj << 5;
        float S = 0.f, Q = 0.f;
        #pragma unroll
        for (int it = 0; it < 18; ++it) {
            int t = lane + (it << 6);
            if (t < 1105) {                    // 65 rows x 17 float4-slots
                int r = t / 17, c4 = t - 17 * r;
                const float* rp = &plane[(r0 + r) * WW + c0 + (c4 << 2)];
                float4 v = *reinterpret_cast<const float4*>(rp);
                if (c4 == 16) { v.y = 0.f; v.z = 0.f; v.w = 0.f; } // cols 65..67 masked
                S += (v.x + v.y) + (v.z + v.w);
                Q = fmaf(v.x, v.x, Q); Q = fmaf(v.y, v.y, Q);
                Q = fmaf(v.z, v.z, Q); Q = fmaf(v.w, v.w, Q);
            }
        }
        #pragma unroll
        for (int off = 32; off > 0; off >>= 1) {
            S += __shfl_down(S, off);
            Q += __shfl_down(Q, off);
        }
        if (lane == 0) {
            const float inv = 1.f / 4225.f;
            float mean = S * inv;
            float var  = fmaxf(fmaf(-mean, mean, Q * inv), 0.f);
            m65 = mean;
            s65 = sqrtf(var + EPSF);
        }
    }

    // ---- reduce K3 partials across the wave, then one barrier + final reduce ----
    #pragma unroll
    for (int off = 32; off > 0; off >>= 1) {
        a3S += __shfl_down(a3S, off);
        a3D += __shfl_down(a3D, off);
    }
    if (lane == 0) {
        wp[wave][0] = a3S; wp[wave][1] = a3D;
        wp[wave][2] = am34; wp[wave][3] = as34;
        wp[wave][4] = m65;  wp[wave][5] = s65;
    }
    __syncthreads();
    if (tid == 0) {
        float A3 = 0.f, D3 = 0.f, M34 = 0.f, S34 = 0.f, M65 = 0.f, S65 = 0.f;
        #pragma unroll
        for (int w = 0; w < 8; ++w) {
            A3 += wp[w][0]; D3 += wp[w][1];
            M34 += wp[w][2]; S34 += wp[w][3];
            M65 += wp[w][4]; S65 += wp[w][5];
        }
        const float inv3 = 1.f / (9.f * 126.f * 126.f);
        pooled[(0 * N + n) * 512 + c]       = A3 * inv3;
        pooled[(0 * N + n) * 512 + 256 + c] = D3 * inv3;
        pooled[(1 * N + n) * 512 + c]       = M34 * (1.f / 36.f);
        pooled[(1 * N + n) * 512 + 256 + c] = S34 * (1.f / 36.f);
        pooled[(2 * N + n) * 512 + c]       = M65 * 0.25f;
        pooled[(2 * N + n) * 512 + 256 + c] = S65 * 0.25f;
    }
}

__device__ __forceinline__ float leaky(float v) { return v > 0.f ? v : SLOPE * v; }

// Whole MLP for one (k, n) per block. 1024 threads = 16 waves.
// Layer results live in LDS; block-local barriers between layers.
__global__ __launch_bounds__(1024) void mlp_fused(const float* __restrict__ pooled,
                                                  const float* __restrict__ W1, const float* __restrict__ b1,
                                                  const float* __restrict__ W2, const float* __restrict__ b2,
                                                  const float* __restrict__ W3, const float* __restrict__ b3,
                                                  const float* __restrict__ W4, const float* __restrict__ b4,
                                                  const int* __restrict__ label,
                                                  float* __restrict__ losses) {
    __shared__ float x[512];
    __shared__ float h1[256];
    __shared__ float h2[256];
    __shared__ float h3[128];

    const int bk = blockIdx.x;         // k*2 + n
    const int k  = bk >> 1;
    const int tid = threadIdx.x;
    const int wave = tid >> 6, lane = tid & 63;

    if (tid < 128)
        reinterpret_cast<float4*>(x)[tid] =
            reinterpret_cast<const float4*>(pooled + (size_t)bk * 512)[tid];
    __syncthreads();

    // layer 1: 512 -> 256 ; 16 rows per wave
    {
        const float4* x4 = reinterpret_cast<const float4*>(x);
        #pragma unroll 2
        for (int rr = 0; rr < 16; ++rr) {
            int o = (wave << 4) + rr;
            const float4* w4 = reinterpret_cast<const float4*>(W1 + ((size_t)k * 256 + o) * 512);
            float4 wa = w4[lane], wb = w4[lane + 64];
            float4 xa = x4[lane], xb = x4[lane + 64];
            float s = 0.f;
            s = fmaf(wa.x, xa.x, s); s = fmaf(wa.y, xa.y, s);
            s = fmaf(wa.z, xa.z, s); s = fmaf(wa.w, xa.w, s);
            s = fmaf(wb.x, xb.x, s); s = fmaf(wb.y, xb.y, s);
            s = fmaf(wb.z, xb.z, s); s = fmaf(wb.w, xb.w, s);
            #pragma unroll
            for (int off = 32; off > 0; off >>= 1) s += __shfl_down(s, off);
            if (lane == 0) h1[o] = leaky(s + b1[k * 256 + o]);
        }
    }
    __syncthreads();

    // layer 2: 256 -> 256 ; 16 rows per wave
    {
        const float4* h14 = reinterpret_cast<const float4*>(h1);
        #pragma unroll 2
        for (int rr = 0; rr < 16; ++rr) {
            int o = (wave << 4) + rr;
            const float4* w4 = reinterpret_cast<const float4*>(W2 + ((size_t)k * 256 + o) * 256);
            float4 wa = w4[lane], xa = h14[lane];
            float s = 0.f;
            s = fmaf(wa.x, xa.x, s); s = fmaf(wa.y, xa.y, s);
            s = fmaf(wa.z, xa.z, s); s = fmaf(wa.w, xa.w, s);
            #pragma unroll
            for (int off = 32; off > 0; off >>= 1) s += __shfl_down(s, off);
            if (lane == 0) h2[o] = leaky(s + b2[k * 256 + o]);
        }
    }
    __syncthreads();

    // layer 3: 256 -> 128 ; 8 rows per wave
    {
        const float4* h24 = reinterpret_cast<const float4*>(h2);
        #pragma unroll 2
        for (int rr = 0; rr < 8; ++rr) {
            int o = (wave << 3) + rr;
            const float4* w4 = reinterpret_cast<const float4*>(W3 + ((size_t)k * 128 + o) * 256);
            float4 wa = w4[lane], xa = h24[lane];
            float s = 0.f;
            s = fmaf(wa.x, xa.x, s); s = fmaf(wa.y, xa.y, s);
            s = fmaf(wa.z, xa.z, s); s = fmaf(wa.w, xa.w, s);
            #pragma unroll
            for (int off = 32; off > 0; off >>= 1) s += __shfl_down(s, off);
            if (lane == 0) h3[o] = leaky(s + b3[k * 128 + o]);
        }
    }
    __syncthreads();

    // layer 4: 128 -> 1 + loss (wave 0; lanes 0..31 hold one float4 each)
    if (wave == 0) {
        float s = 0.f;
        if (lane < 32) {
            float4 wv = reinterpret_cast<const float4*>(W4 + (size_t)k * 128)[lane];
            float4 hv = reinterpret_cast<const float4*>(h3)[lane];
            s = fmaf(wv.x, hv.x, s); s = fmaf(wv.y, hv.y, s);
            s = fmaf(wv.z, hv.z, s); s = fmaf(wv.w, hv.w, s);
        }
        #pragma unroll
        for (int off = 32; off > 0; off >>= 1) s += __shfl_down(s, off);
        if (lane == 0) {
            float logit = s + b4[k];
            float y = (float)(*label);
            float sp = fmaxf(logit, 0.f) + log1pf(expf(-fabsf(logit)));
            losses[bk] = sp - logit * y;
        }
    }
}

// Deterministic 6-value finalize: sum_k mean_n loss[k][n]
__global__ void finalize_kernel(const float* __restrict__ losses, float* __restrict__ out) {
    if (threadIdx.x == 0 && blockIdx.x == 0) {
        float tot = 0.f;
        #pragma unroll
        for (int k = 0; k < 3; ++k)
            tot += (losses[k * 2 + 0] + losses[k * 2 + 1]) / 2.f;
        out[0] = tot;
    }
}

extern "C" void kernel_launch(void* const* d_in, const int* in_sizes, int n_in,
                              void* d_out, int out_size, void* d_ws, size_t ws_size,
                              hipStream_t stream) {
    const float* feat = (const float*)d_in[0];
    const float* W1   = (const float*)d_in[1];
    const float* b1   = (const float*)d_in[2];
    const float* W2   = (const float*)d_in[3];
    const float* b2   = (const float*)d_in[4];
    const float* W3   = (const float*)d_in[5];
    const float* b3   = (const float*)d_in[6];
    const float* W4   = (const float*)d_in[7];
    const float* b4   = (const float*)d_in[8];
    const int* label  = (const int*)d_in[9];

    const int N = in_sizes[0] / (CCH * HH * WW);   // = 2

    float* pooled = (float*)d_ws;                   // [3][N][512]
    float* losses = pooled + (size_t)3 * N * 512;   // [3][N]

    stats_kernel<<<N * CCH, 512, 0, stream>>>(feat, pooled, N);
    mlp_fused<<<3 * N, 1024, 0, stream>>>(pooled, W1, b1, W2, b2, W3, b3, W4, b4,
                                          label, losses);
    finalize_kernel<<<1, 64, 0, stream>>>(losses, (float*)d_out);
}

// Round 7
// 33.750 us; speedup vs baseline: 1.7327x; 1.7327x over previous
//
#include <hip/hip_runtime.h>
#include <hip/hip_bf16.h>
#include <math.h>

#define CCH   256      // IN_CHANNELS
#define HH    128
#define WW    128
#define EPSF  1e-12f
#define EPS81 8.1e-11f // 81 * 1e-12
#define SLOPE 0.2f

// pooled layout: [3][N][512]  (c -> mean part, 256+c -> std part)

__device__ __forceinline__ void k3_loadrow(const float* __restrict__ plane, int r, int jb,
                                           float4& rs, float4& rq) {
    const float* rp = &plane[r * WW + jb];
    float4 v = *reinterpret_cast<const float4*>(rp);       // cols jb..jb+3 (16B aligned)
    float2 w = *reinterpret_cast<const float2*>(rp + 4);   // cols jb+4, jb+5 (8B aligned)
    float t12 = v.y + v.z, t34 = v.w + w.x;
    rs.x = v.x + t12; rs.y = t12 + v.w; rs.z = v.z + t34; rs.w = t34 + w.y;
    float y0 = v.x * v.x, y1 = v.y * v.y, y2 = v.z * v.z;
    float y3 = v.w * v.w, y4 = w.x * w.x, y5 = w.y * w.y;
    float u12 = y1 + y2, u34 = y3 + y4;
    rq.x = y0 + u12; rq.y = u12 + y3; rq.z = y2 + u34; rq.w = u34 + y5;
}

__device__ __forceinline__ void win_acc(float S, float Q, float wm, float& aS, float& aD) {
    // std*9 = sqrt(max(9Q - S^2, 0) + 81*eps); accumulate masked
    float d = fmaxf(fmaf(S, -S, 9.f * Q), 0.f);
    aS = fmaf(wm, S, aS);
    aD = fmaf(wm, sqrtf(d + EPS81), aD);
}

__global__ __launch_bounds__(512, 4) void stats_kernel(const float* __restrict__ feat,
                                                       float* __restrict__ pooled,
                                                       int N) {
    __shared__ float plane[HH * WW + 8];      // 64 KB + pad
    __shared__ float wp[8][6];

    const int p    = blockIdx.x;              // n*C + c
    const int n    = p >> 8;
    const int c    = p & 255;
    const int tid  = threadIdx.x;
    const int wave = tid >> 6, lane = tid & 63;

    // ---- stage plane into LDS via async global->LDS (16B/lane, linear layout) ----
    {
        const float* gbase = feat + (size_t)p * (HH * WW) + (tid << 2);
        #pragma unroll
        for (int i = 0; i < 8; ++i) {
            __builtin_amdgcn_global_load_lds(
                (const __attribute__((address_space(1))) void*)(gbase + i * 2048),
                (__attribute__((address_space(3))) void*)&plane[i * 2048 + (wave << 8)],
                16, 0, 0);
        }
        if (tid < 8) plane[HH * WW + tid] = 0.f;
    }
    __syncthreads();

    // =============== K = 3, stride 1, out 126x126 ===============
    // thread = (strip s: window cols 4s..4s+3, rowgroup g: window rows 8g..8g+7)
    // Branchless: all 8 row-steps run; invalid windows masked; row index clamped.
    float a3S = 0.f, a3D = 0.f;
    {
        const int s  = tid & 31;
        const int g  = tid >> 5;              // 0..15
        const int jb = s << 2;
        const float wm2 = (s < 31) ? 1.f : 0.f;  // window cols 4s+2,4s+3 invalid for s=31
        const int i0 = g << 3;
        float4 r0s, r0q, r1s, r1q;
        k3_loadrow(plane, i0,     jb, r0s, r0q);
        k3_loadrow(plane, i0 + 1, jb, r1s, r1q);
        #pragma unroll
        for (int t = 0; t < 8; ++t) {
            const int i  = i0 + t;
            const int r2 = (i + 2 < 128) ? (i + 2) : 127;   // clamp (g=15 tail)
            float4 r2s, r2q;
            k3_loadrow(plane, r2, jb, r2s, r2q);
            const float wr  = (i < 126) ? 1.f : 0.f;        // row validity mask
            const float wrm = wr * wm2;
            float Sx = r0s.x + r1s.x + r2s.x, Qx = r0q.x + r1q.x + r2q.x;
            float Sy = r0s.y + r1s.y + r2s.y, Qy = r0q.y + r1q.y + r2q.y;
            float Sz = r0s.z + r1s.z + r2s.z, Qz = r0q.z + r1q.z + r2q.z;
            float Sw = r0s.w + r1s.w + r2s.w, Qw = r0q.w + r1q.w + r2q.w;
            win_acc(Sx, Qx, wr,  a3S, a3D);
            win_acc(Sy, Qy, wr,  a3S, a3D);
            win_acc(Sz, Qz, wrm, a3S, a3D);
            win_acc(Sw, Qw, wrm, a3S, a3D);
            r0s = r1s; r0q = r1q; r1s = r2s; r1q = r2q;
        }
    }

    // =============== K = 34, stride 16, out 6x6 (windows round-robin over 8 waves) ===============
    float am34 = 0.f, as34 = 0.f;
    for (int w = wave; w < 36; w += 8) {
        int wi = w / 6, wj = w - 6 * wi;
        int r0 = wi << 4, c0 = wj << 4;
        float S = 0.f, Q = 0.f;
        #pragma unroll
        for (int it = 0; it < 5; ++it) {
            int t = lane + (it << 6);
            if (t < 306) {                     // 34 rows x 9 float4-slots
                int r = t / 9, c4 = t - 9 * r;
                const float* rp = &plane[(r0 + r) * WW + c0 + (c4 << 2)];
                float4 v = *reinterpret_cast<const float4*>(rp);
                if (c4 == 8) { v.z = 0.f; v.w = 0.f; }   // cols 34,35 of window masked
                S += (v.x + v.y) + (v.z + v.w);
                Q = fmaf(v.x, v.x, Q); Q = fmaf(v.y, v.y, Q);
                Q = fmaf(v.z, v.z, Q); Q = fmaf(v.w, v.w, Q);
            }
        }
        #pragma unroll
        for (int off = 32; off > 0; off >>= 1) {
            S += __shfl_down(S, off);
            Q += __shfl_down(Q, off);
        }
        if (lane == 0) {
            const float inv = 1.f / 1156.f;
            float mean = S * inv;
            float var  = fmaxf(fmaf(-mean, mean, Q * inv), 0.f);
            am34 += mean;
            as34 += sqrtf(var + EPSF);
        }
    }

    // =============== K = 65, stride 32, out 2x2 (one window per wave, waves 4..7) ===============
    float m65 = 0.f, s65 = 0.f;
    if (wave >= 4) {
        int w  = wave - 4;
        int wi = w >> 1, wj = w & 1;
        int r0 = wi << 5, c0 = wj << 5;
        float S = 0.f, Q = 0.f;
        #pragma unroll
        for (int it = 0; it < 18; ++it) {
            int t = lane + (it << 6);
            if (t < 1105) {                    // 65 rows x 17 float4-slots
                int r = t / 17, c4 = t - 17 * r;
                const float* rp = &plane[(r0 + r) * WW + c0 + (c4 << 2)];
                float4 v = *reinterpret_cast<const float4*>(rp);
                if (c4 == 16) { v.y = 0.f; v.z = 0.f; v.w = 0.f; } // cols 65..67 masked
                S += (v.x + v.y) + (v.z + v.w);
                Q = fmaf(v.x, v.x, Q); Q = fmaf(v.y, v.y, Q);
                Q = fmaf(v.z, v.z, Q); Q = fmaf(v.w, v.w, Q);
            }
        }
        #pragma unroll
        for (int off = 32; off > 0; off >>= 1) {
            S += __shfl_down(S, off);
            Q += __shfl_down(Q, off);
        }
        if (lane == 0) {
            const float inv = 1.f / 4225.f;
            float mean = S * inv;
            float var  = fmaxf(fmaf(-mean, mean, Q * inv), 0.f);
            m65 = mean;
            s65 = sqrtf(var + EPSF);
        }
    }

    // ---- reduce K3 partials across the wave, then one barrier + final reduce ----
    #pragma unroll
    for (int off = 32; off > 0; off >>= 1) {
        a3S += __shfl_down(a3S, off);
        a3D += __shfl_down(a3D, off);
    }
    if (lane == 0) {
        wp[wave][0] = a3S; wp[wave][1] = a3D;
        wp[wave][2] = am34; wp[wave][3] = as34;
        wp[wave][4] = m65;  wp[wave][5] = s65;
    }
    __syncthreads();
    if (tid == 0) {
        float A3 = 0.f, D3 = 0.f, M34 = 0.f, S34 = 0.f, M65 = 0.f, S65 = 0.f;
        #pragma unroll
        for (int w = 0; w < 8; ++w) {
            A3 += wp[w][0]; D3 += wp[w][1];
            M34 += wp[w][2]; S34 += wp[w][3];
            M65 += wp[w][4]; S65 += wp[w][5];
        }
        const float inv3 = 1.f / (9.f * 126.f * 126.f);
        pooled[(0 * N + n) * 512 + c]       = A3 * inv3;
        pooled[(0 * N + n) * 512 + 256 + c] = D3 * inv3;
        pooled[(1 * N + n) * 512 + c]       = M34 * (1.f / 36.f);
        pooled[(1 * N + n) * 512 + 256 + c] = S34 * (1.f / 36.f);
        pooled[(2 * N + n) * 512 + c]       = M65 * 0.25f;
        pooled[(2 * N + n) * 512 + 256 + c] = S65 * 0.25f;
    }
}

__device__ __forceinline__ float leaky(float v) { return v > 0.f ? v : SLOPE * v; }

// One wave per output row (k, o); float4 loads; both n samples per weight read.
__global__ __launch_bounds__(256) void layer_kernel(const float* __restrict__ W,
                                                    const float* __restrict__ b,
                                                    const float* __restrict__ xin,
                                                    float* __restrict__ xout,
                                                    int DIN, int DOUT, int act) {
    const int wave = threadIdx.x >> 6, lane = threadIdx.x & 63;
    const int r = blockIdx.x * 4 + wave;           // row over 3*DOUT
    if (r >= 3 * DOUT) return;
    const int k = r / DOUT, o = r - k * DOUT;
    const int DIN4 = DIN >> 2;

    const float4* w4  = reinterpret_cast<const float4*>(W + ((size_t)k * DOUT + o) * DIN);
    const float4* x04 = reinterpret_cast<const float4*>(xin + (size_t)(k * 2 + 0) * DIN);
    const float4* x14 = reinterpret_cast<const float4*>(xin + (size_t)(k * 2 + 1) * DIN);

    float s0 = 0.f, s1 = 0.f;
    for (int j = lane; j < DIN4; j += 64) {
        float4 wv = w4[j], a = x04[j], d = x14[j];
        s0 = fmaf(wv.x, a.x, s0); s0 = fmaf(wv.y, a.y, s0);
        s0 = fmaf(wv.z, a.z, s0); s0 = fmaf(wv.w, a.w, s0);
        s1 = fmaf(wv.x, d.x, s1); s1 = fmaf(wv.y, d.y, s1);
        s1 = fmaf(wv.z, d.z, s1); s1 = fmaf(wv.w, d.w, s1);
    }
    #pragma unroll
    for (int off = 32; off > 0; off >>= 1) {
        s0 += __shfl_down(s0, off);
        s1 += __shfl_down(s1, off);
    }
    if (lane == 0) {
        float bb = b[k * DOUT + o];
        float v0 = s0 + bb, v1 = s1 + bb;
        if (act) { v0 = leaky(v0); v1 = leaky(v1); }
        xout[(size_t)(k * 2 + 0) * DOUT + o] = v0;
        xout[(size_t)(k * 2 + 1) * DOUT + o] = v1;
    }
}

// Final layer 128->1 + softplus loss + deterministic total. One block, 384 threads:
// one wave per (k, n); thread 0 then combines the 6 losses.
__global__ __launch_bounds__(384) void final_kernel(const float* __restrict__ W4,
                                                    const float* __restrict__ b4,
                                                    const float* __restrict__ h3,
                                                    const int* __restrict__ label,
                                                    float* __restrict__ out) {
    __shared__ float lossArr[6];
    const int wave = threadIdx.x >> 6, lane = threadIdx.x & 63;
    {
        const int k = wave >> 1, n = wave & 1;
        const float* w = &W4[(size_t)k * 128];
        const float* x = &h3[(size_t)(k * 2 + n) * 128];
        float s = w[lane] * x[lane] + w[lane + 64] * x[lane + 64];
        #pragma unroll
        for (int off = 32; off > 0; off >>= 1) s += __shfl_down(s, off);
        if (lane == 0) {
            float logit = s + b4[k];
            float y = (float)(*label);
            float sp = fmaxf(logit, 0.f) + log1pf(expf(-fabsf(logit)));
            lossArr[wave] = sp - logit * y;
        }
    }
    __syncthreads();
    if (threadIdx.x == 0) {
        float tot = 0.f;
        #pragma unroll
        for (int k = 0; k < 3; ++k)
            tot += (lossArr[k * 2 + 0] + lossArr[k * 2 + 1]) * 0.5f;
        out[0] = tot;
    }
}

extern "C" void kernel_launch(void* const* d_in, const int* in_sizes, int n_in,
                              void* d_out, int out_size, void* d_ws, size_t ws_size,
                              hipStream_t stream) {
    const float* feat = (const float*)d_in[0];
    const float* W1   = (const float*)d_in[1];
    const float* b1   = (const float*)d_in[2];
    const float* W2   = (const float*)d_in[3];
    const float* b2   = (const float*)d_in[4];
    const float* W3   = (const float*)d_in[5];
    const float* b3   = (const float*)d_in[6];
    const float* W4   = (const float*)d_in[7];
    const float* b4   = (const float*)d_in[8];
    const int* label  = (const int*)d_in[9];

    const int N = in_sizes[0] / (CCH * HH * WW);   // = 2

    float* pooled = (float*)d_ws;                   // [3][N][512]
    float* h1     = pooled + (size_t)3 * N * 512;   // [3][N][256]
    float* h2     = h1     + (size_t)3 * N * 256;   // [3][N][256]
    float* h3     = h2     + (size_t)3 * N * 256;   // [3][N][128]

    stats_kernel<<<N * CCH, 512, 0, stream>>>(feat, pooled, N);

    layer_kernel<<<192, 256, 0, stream>>>(W1, b1, pooled, h1, 512, 256, 1);
    layer_kernel<<<192, 256, 0, stream>>>(W2, b2, h1, h2, 256, 256, 1);
    layer_kernel<<<96, 256, 0, stream>>>(W3, b3, h2, h3, 256, 128, 1);
    final_kernel<<<1, 384, 0, stream>>>(W4, b4, h3, label, (float*)d_out);
}